// Round 8
// baseline (85.754 us; speedup 1.0000x reference)
//
#include <hip/hip_runtime.h>
#include <hip/hip_fp16.h>
#include <math.h>

#define N_PIX (256 * 256)
#define N_PTS 192
#define SEGS 8
#define TILE_PIX 64                     // 8x8 pixel tile per block
#define N_BLK (N_PIX / TILE_PIX)        // 1024 blocks
#define THREADS (TILE_PIX * SEGS)       // 512 threads = 8 waves
#define VOL_ELEMS (128 * 128 * 128)     // voxels; vol8 = 16B each = 32 MB

// ---- prep: pack 8 fp16 corners per voxel into 16B ----
// layout: {v(z,y,x), v(z,y,x1), v(z,y1,x), v(z,y1,x1),
//          v(z1,y,x), v(z1,y,x1), v(z1,y1,x), v(z1,y1,x1)}  (x1/y1/z1 clamped)
__global__ __launch_bounds__(256) void pack_kernel(
    const float* __restrict__ vol, uint4* __restrict__ vol8)
{
    const int idx = blockIdx.x * 256 + threadIdx.x;   // z*16384 + y*128 + x
    const int x = idx & 127;
    const int y = (idx >> 7) & 127;
    const int z = idx >> 14;
    const int x1 = min(x + 1, 127);
    const int y1 = min(y + 1, 127);
    const int z1 = min(z + 1, 127);
    const float* p00 = vol + (z  * 128 + y ) * 128;
    const float* p01 = vol + (z  * 128 + y1) * 128;
    const float* p10 = vol + (z1 * 128 + y ) * 128;
    const float* p11 = vol + (z1 * 128 + y1) * 128;
    const __half2 h0 = __floats2half2_rn(p00[x], p00[x1]);
    const __half2 h1 = __floats2half2_rn(p01[x], p01[x1]);
    const __half2 h2 = __floats2half2_rn(p10[x], p10[x1]);
    const __half2 h3 = __floats2half2_rn(p11[x], p11[x1]);
    uint4 o;
    o.x = *(const unsigned int*)&h0;
    o.y = *(const unsigned int*)&h1;
    o.z = *(const unsigned int*)&h2;
    o.w = *(const unsigned int*)&h3;
    vol8[idx] = o;
}

__global__ __launch_bounds__(THREADS) void render_kernel(
    const uint4* __restrict__ vol8,
    const float* __restrict__ Rm,
    const float* __restrict__ Tv,
    float* __restrict__ out,            // gray image (pre-normalization)
    float* __restrict__ part)           // [4][N_BLK] sum, sq, min, max
{
    const int tid = threadIdx.x;
    const int seg = tid >> 6;           // wave index = depth segment
    const int l   = tid & 63;           // lane = pixel within 8x8 tile
    const int tr  = blockIdx.x >> 5;    // 32x32 grid of 8x8 tiles
    const int tc  = blockIdx.x & 31;
    const int h = tr * 8 + (l >> 3);
    const int w = tc * 8 + (l & 7);
    const float yg = 1.0f - (2.0f / 255.0f) * (float)h;
    const float xg = 1.0f - (2.0f / 255.0f) * (float)w;

    const float r00 = Rm[0], r01 = Rm[1], r02 = Rm[2];
    const float r10 = Rm[3], r11 = Rm[4], r12 = Rm[5];
    const float r20 = Rm[6], r21 = Rm[7], r22 = Rm[8];
    const float t0 = Tv[0], t1 = Tv[1], t2 = Tv[2];

    // world_i(d) = a_i * d + b_i  (linear in depth)
    const float a0 = 0.25f * (r00 * xg + r01 * yg) + r02;
    const float a1 = 0.25f * (r10 * xg + r11 * yg) + r12;
    const float a2 = 0.25f * (r20 * xg + r21 * yg) + r22;
    const float b0 = -(r00 * t0 + r01 * t1 + r02 * t2);
    const float b1 = -(r10 * t0 + r11 * t1 + r12 * t2);
    const float b2 = -(r20 * t0 + r21 * t1 + r22 * t2);

    // ---- analytic valid-depth interval: all axes need |a*d+b| < 1 + 2/127 ----
    const float LIM = 1.0f + 2.0f / 127.0f + 1e-4f;
    float dlo = 3.0f, dhi = 9.0f;
    {
        const float aa[3] = {a0, a1, a2};
        const float bb[3] = {b0, b1, b2};
        #pragma unroll
        for (int k = 0; k < 3; ++k) {
            const float a = aa[k], b = bb[k];
            if (fabsf(a) > 1e-12f) {
                const float i0 = (-LIM - b) / a;
                const float i1 = ( LIM - b) / a;
                dlo = fmaxf(dlo, fminf(i0, i1));
                dhi = fminf(dhi, fmaxf(i0, i1));
            } else if (fabsf(b) >= LIM) {
                dhi = -1e30f;   // ray never enters the volume on this axis
            }
        }
    }
    const float step = 6.0f / 191.0f;
    const float rstep = 191.0f / 6.0f;
    int plo = (int)ceilf((dlo - 3.0f) * rstep - 1e-3f);
    int phi = (int)floorf((dhi - 3.0f) * rstep + 1e-3f);
    plo = max(plo, 0);
    phi = min(phi, N_PTS - 1);
    int len = phi - plo + 1;
    if (len < 0) len = 0;
    const int chunk = (len + SEGS - 1) >> 3;
    const int iBeg = plo + seg * chunk;
    const int iEnd = min(iBeg + chunk, plo + len);

    float P = 1.0f;   // product of (1+1e-10 - dens) within my chunk
    float U = 1.0f;   // product of (1 - dens) within my chunk
    float S = 0.0f;   // sum dens * local_absorption * feat within my chunk

    #pragma unroll 4
    for (int p = iBeg; p < iEnd; ++p) {
        const float d = fmaf(step, (float)p, 3.0f);
        const float fx = (fmaf(a0, d, b0) + 1.0f) * 63.5f;
        const float fy = (fmaf(a1, d, b1) + 1.0f) * 63.5f;
        const float fz = (fmaf(a2, d, b2) + 1.0f) * 63.5f;
        const float x0f = floorf(fx), y0f = floorf(fy), z0f = floorf(fz);
        const float wx = fx - x0f, wy = fy - y0f, wz = fz - z0f;
        const int ix = (int)x0f, iy = (int)y0f, iz = (int)z0f;
        // validity folded into per-axis weights
        const float ax0 = (ix >= 0  && ix <= 127) ? (1.0f - wx) : 0.0f;
        const float ax1 = (ix >= -1 && ix <= 126) ? wx : 0.0f;
        const float ay0 = (iy >= 0  && iy <= 127) ? (1.0f - wy) : 0.0f;
        const float ay1 = (iy >= -1 && iy <= 126) ? wy : 0.0f;
        const float az0 = (iz >= 0  && iz <= 127) ? (1.0f - wz) : 0.0f;
        const float az1 = (iz >= -1 && iz <= 126) ? wz : 0.0f;
        const float s = (ax0 + ax1) * (ay0 + ay1) * (az0 + az1);
        const float dens = s * (1.0f / 192.0f);

        // per-axis edge remap onto the packed base voxel (exact vs ref clamp+mask)
        int xi = ix; float wx0 = ax0, wx1 = ax1;
        if (xi < 0) { xi = 0; wx0 = ax1; wx1 = 0.0f; } else { xi = min(xi, 127); }
        int yi = iy; float wy0 = ay0, wy1 = ay1;
        if (yi < 0) { yi = 0; wy0 = ay1; wy1 = 0.0f; } else { yi = min(yi, 127); }
        int zi = iz; float wz0 = az0, wz1 = az1;
        if (zi < 0) { zi = 0; wz0 = az1; wz1 = 0.0f; } else { zi = min(zi, 127); }

        const uint4 raw = vol8[(zi * 128 + yi) * 128 + xi];
        const __half2 h0 = *(const __half2*)&raw.x;   // c000, c001
        const __half2 h1 = *(const __half2*)&raw.y;   // c010, c011
        const __half2 h2 = *(const __half2*)&raw.z;   // c100, c101
        const __half2 h3 = *(const __half2*)&raw.w;   // c110, c111
        const float bil0 = wy0 * fmaf(wx0, __low2float(h0), wx1 * __high2float(h0))
                         + wy1 * fmaf(wx0, __low2float(h1), wx1 * __high2float(h1));
        const float bil1 = wy0 * fmaf(wx0, __low2float(h2), wx1 * __high2float(h2))
                         + wy1 * fmaf(wx0, __low2float(h3), wx1 * __high2float(h3));
        const float feat = fmaf(wz0, bil0, wz1 * bil1);

        S = fmaf(dens * P, feat, S);
        P *= (1.0f + 1e-10f - dens);
        U *= (1.0f - dens);
    }

    // ---- per-(seg,pixel) partials to LDS; wave 0 combines sequentially ----
    __shared__ float sP[SEGS][TILE_PIX];
    __shared__ float sU[SEGS][TILE_PIX];
    __shared__ float sS[SEGS][TILE_PIX];
    sP[seg][l] = P;
    sU[seg][l] = U;
    sS[seg][l] = S;
    __syncthreads();

    if (tid < TILE_PIX) {
        float absorb = 1.0f, uAll = 1.0f, wS = 0.0f;
        #pragma unroll
        for (int s = 0; s < SEGS; ++s) {
            wS = fmaf(absorb, sS[s][l], wS);
            absorb *= sP[s][l];
            uAll   *= sU[s][l];
        }
        const float g = (3.0f * wS + (1.0f - uAll)) * 0.25f;
        out[h * 256 + w] = g;

        // wave-0 stats reduction over the 64 tile pixels
        float vs = g, vq = g * g, vmn = g, vmx = g;
        #pragma unroll
        for (int off = 1; off < 64; off <<= 1) {
            vs += __shfl_xor(vs, off);
            vq += __shfl_xor(vq, off);
            vmn = fminf(vmn, __shfl_xor(vmn, off));
            vmx = fmaxf(vmx, __shfl_xor(vmx, off));
        }
        if (l == 0) {
            part[blockIdx.x]             = vs;
            part[N_BLK + blockIdx.x]     = vq;
            part[2 * N_BLK + blockIdx.x] = vmn;
            part[3 * N_BLK + blockIdx.x] = vmx;
        }
    }
}

// Every block redundantly reduces the 1024 partials (L2/L3-hot),
// then normalizes its own 256 pixels. No cross-block ordering needed.
__global__ __launch_bounds__(256) void finish_kernel(
    float* __restrict__ out,
    const float* __restrict__ part)
{
    const int tid = threadIdx.x;
    __shared__ float s_s[4], s_q[4], s_n[4], s_x[4];
    __shared__ float s_fin[4];

    float fs  = part[tid]               + part[tid + 256]
              + part[tid + 512]         + part[tid + 768];
    float fq  = part[N_BLK + tid]       + part[N_BLK + tid + 256]
              + part[N_BLK + tid + 512] + part[N_BLK + tid + 768];
    float fn  = fminf(fminf(part[2 * N_BLK + tid],       part[2 * N_BLK + tid + 256]),
                      fminf(part[2 * N_BLK + tid + 512], part[2 * N_BLK + tid + 768]));
    float fx2 = fmaxf(fmaxf(part[3 * N_BLK + tid],       part[3 * N_BLK + tid + 256]),
                      fmaxf(part[3 * N_BLK + tid + 512], part[3 * N_BLK + tid + 768]));
    #pragma unroll
    for (int off = 1; off < 64; off <<= 1) {
        fs += __shfl_xor(fs, off);
        fq += __shfl_xor(fq, off);
        fn  = fminf(fn,  __shfl_xor(fn, off));
        fx2 = fmaxf(fx2, __shfl_xor(fx2, off));
    }
    const int wave = tid >> 6;
    const int lane = tid & 63;
    if (lane == 0) { s_s[wave] = fs; s_q[wave] = fq; s_n[wave] = fn; s_x[wave] = fx2; }
    __syncthreads();
    if (tid == 0) {
        const float tsum = s_s[0] + s_s[1] + s_s[2] + s_s[3];
        const float tsq  = s_q[0] + s_q[1] + s_q[2] + s_q[3];
        const float tmn  = fminf(fminf(s_n[0], s_n[1]), fminf(s_n[2], s_n[3]));
        const float tmx  = fmaxf(fmaxf(s_x[0], s_x[1]), fmaxf(s_x[2], s_x[3]));
        const float N = (float)N_PIX;
        const float mean = tsum / N;
        float var = (tsq - N * mean * mean) / (N - 1.0f);
        if (var < 0.0f) var = 0.0f;
        const float denom = sqrtf(var) + 1e-8f;
        s_fin[0] = mean;
        s_fin[1] = denom;
        s_fin[2] = (tmn - mean) / denom;   // std.min
        s_fin[3] = (tmx - mean) / denom;   // std.max
    }
    __syncthreads();

    const float mean = s_fin[0];
    const float rdenom = 1.0f / s_fin[1];
    const float smin = s_fin[2];
    const float rrange = 1.0f / (s_fin[3] - smin + 1e-8f);
    const int i = blockIdx.x * 256 + tid;
    const float sv = (out[i] - mean) * rdenom;
    out[i] = (sv - smin + 1e-8f) * rrange;
}

extern "C" void kernel_launch(void* const* d_in, const int* in_sizes, int n_in,
                              void* d_out, int out_size, void* d_ws, size_t ws_size,
                              hipStream_t stream)
{
    const float* vol = (const float*)d_in[0];
    const float* Rm  = (const float*)d_in[1];
    const float* Tv  = (const float*)d_in[2];
    float* out = (float*)d_out;
    uint4* vol8 = (uint4*)d_ws;                          // 32 MB
    float* part = (float*)((char*)d_ws + VOL_ELEMS * 16); // 16 KB after vol8

    hipLaunchKernelGGL(pack_kernel, dim3(VOL_ELEMS / 256), dim3(256), 0, stream,
                       vol, (uint4*)d_ws);
    hipLaunchKernelGGL(render_kernel, dim3(N_BLK), dim3(THREADS), 0, stream,
                       vol8, Rm, Tv, out, part);
    hipLaunchKernelGGL(finish_kernel, dim3(N_PIX / 256), dim3(256), 0, stream,
                       out, part);
}

// Round 9
// 78.343 us; speedup vs baseline: 1.0946x; 1.0946x over previous
//
#include <hip/hip_runtime.h>
#include <math.h>

#define N_PIX (256 * 256)
#define N_PTS 192
#define SEGS 8
#define TILE_PIX 64                     // 8x8 pixel tile per block
#define N_BLK (N_PIX / TILE_PIX)        // 1024 blocks
#define THREADS (TILE_PIX * SEGS)       // 512 threads = 8 waves

// log2(1 - 1/192); also used for (1 + 1e-10 - 1/192) (diff ~1e-10, negligible)
#define L2Q  (-0.0075336725f)
#define QF   (0.99479166677f)           // 1 + 1e-10 - 1/192

// general (boundary) step: full masks + clamped loads; exact vs reference
__device__ __forceinline__ void general_step(
    const float* __restrict__ vol, float pf,
    float A0, float B0, float A1, float B1, float A2, float B2,
    float& S, float& Prun)
{
    const float fx = fmaf(A0, pf, B0);
    const float fy = fmaf(A1, pf, B1);
    const float fz = fmaf(A2, pf, B2);
    const float x0f = floorf(fx), y0f = floorf(fy), z0f = floorf(fz);
    const float wx = fx - x0f, wy = fy - y0f, wz = fz - z0f;
    const int ix = (int)x0f, iy = (int)y0f, iz = (int)z0f;
    const float ax0 = (ix >= 0  && ix <= 127) ? (1.0f - wx) : 0.0f;
    const float ax1 = (ix >= -1 && ix <= 126) ? wx : 0.0f;
    const float ay0 = (iy >= 0  && iy <= 127) ? (1.0f - wy) : 0.0f;
    const float ay1 = (iy >= -1 && iy <= 126) ? wy : 0.0f;
    const float az0 = (iz >= 0  && iz <= 127) ? (1.0f - wz) : 0.0f;
    const float az1 = (iz >= -1 && iz <= 126) ? wz : 0.0f;
    const float s = (ax0 + ax1) * (ay0 + ay1) * (az0 + az1);
    const float dens = s * (1.0f / 192.0f);
    const int xc0 = min(max(ix, 0), 127), xc1 = min(max(ix + 1, 0), 127);
    const int yc0 = min(max(iy, 0), 127), yc1 = min(max(iy + 1, 0), 127);
    const int zc0 = min(max(iz, 0), 127), zc1 = min(max(iz + 1, 0), 127);
    const float* q00 = vol + (zc0 * 128 + yc0) * 128;
    const float* q01 = vol + (zc0 * 128 + yc1) * 128;
    const float* q10 = vol + (zc1 * 128 + yc0) * 128;
    const float* q11 = vol + (zc1 * 128 + yc1) * 128;
    const float feat =
        az0 * (ay0 * (ax0 * q00[xc0] + ax1 * q00[xc1]) +
               ay1 * (ax0 * q01[xc0] + ax1 * q01[xc1])) +
        az1 * (ay0 * (ax0 * q10[xc0] + ax1 * q10[xc1]) +
               ay1 * (ax0 * q11[xc0] + ax1 * q11[xc1]));
    S = fmaf(dens * Prun, feat, S);
    Prun *= (1.0f + 1e-10f - dens);
}

__global__ __launch_bounds__(THREADS) void render_kernel(
    const float* __restrict__ vol,
    const float* __restrict__ Rm,
    const float* __restrict__ Tv,
    float* __restrict__ out,            // gray image (pre-normalization)
    float* __restrict__ part)           // [4][N_BLK] sum, sq, min, max
{
    const int tid = threadIdx.x;
    const int seg = tid >> 6;           // wave index = depth segment
    const int l   = tid & 63;           // lane = pixel within 8x8 tile
    const int tr  = blockIdx.x >> 5;    // 32x32 grid of 8x8 tiles
    const int tc  = blockIdx.x & 31;
    const int h = tr * 8 + (l >> 3);
    const int w = tc * 8 + (l & 7);
    const float yg = 1.0f - (2.0f / 255.0f) * (float)h;
    const float xg = 1.0f - (2.0f / 255.0f) * (float)w;

    const float r00 = Rm[0], r01 = Rm[1], r02 = Rm[2];
    const float r10 = Rm[3], r11 = Rm[4], r12 = Rm[5];
    const float r20 = Rm[6], r21 = Rm[7], r22 = Rm[8];
    const float t0 = Tv[0], t1 = Tv[1], t2 = Tv[2];

    // world_i(d) = a_i * d + b_i  (linear in depth d)
    const float a0 = 0.25f * (r00 * xg + r01 * yg) + r02;
    const float a1 = 0.25f * (r10 * xg + r11 * yg) + r12;
    const float a2 = 0.25f * (r20 * xg + r21 * yg) + r22;
    const float b0 = -(r00 * t0 + r01 * t1 + r02 * t2);
    const float b1 = -(r10 * t0 + r11 * t1 + r12 * t2);
    const float b2 = -(r20 * t0 + r21 * t1 + r22 * t2);

    const float step = 6.0f / 191.0f;
    const float rstep = 191.0f / 6.0f;

    // voxel coords as linear fn of sample index p: f_i(p) = A_i*p + B_i
    const float A0 = a0 * step * 63.5f, B0 = (fmaf(a0, 3.0f, b0) + 1.0f) * 63.5f;
    const float A1 = a1 * step * 63.5f, B1 = (fmaf(a1, 3.0f, b1) + 1.0f) * 63.5f;
    const float A2 = a2 * step * 63.5f, B2 = (fmaf(a2, 3.0f, b2) + 1.0f) * 63.5f;

    // ---- outer valid interval: any corner in-bounds: |a*d+b| < 1 + 2/127 ----
    const float LIM = 1.0f + 2.0f / 127.0f + 1e-4f;
    // ---- interior interval: all weights valid & s==1: a*d+b in [-1, 1) ----
    const float WHI = 1.0f - 1e-5f;
    float dlo = 3.0f, dhi = 9.0f;       // outer, in d-units
    float dloI = 3.0f, dhiI = 9.0f;     // interior
    {
        const float aa[3] = {a0, a1, a2};
        const float bb[3] = {b0, b1, b2};
        #pragma unroll
        for (int k = 0; k < 3; ++k) {
            const float a = aa[k], b = bb[k];
            if (fabsf(a) > 1e-12f) {
                const float ra = 1.0f / a;
                const float o0 = (-LIM - b) * ra, o1 = (LIM - b) * ra;
                dlo = fmaxf(dlo, fminf(o0, o1));
                dhi = fminf(dhi, fmaxf(o0, o1));
                const float i0 = (-1.0f - b) * ra, i1 = (WHI - b) * ra;
                dloI = fmaxf(dloI, fminf(i0, i1));
                dhiI = fminf(dhiI, fmaxf(i0, i1));
            } else {
                if (fabsf(b) >= LIM) dhi = -1e30f;
                if (b < -1.0f || b > WHI) dhiI = -1e30f;
            }
        }
    }
    int plo = (int)ceilf((dlo - 3.0f) * rstep - 1e-3f);
    int phi = (int)floorf((dhi - 3.0f) * rstep + 1e-3f);
    plo = max(plo, 0);
    phi = min(phi, N_PTS - 1);
    int len = phi - plo + 1;
    if (len < 0) { len = 0; phi = plo - 1; }
    // interior clipped; safety margins push uncertain samples to general path
    int plo2 = (int)ceilf((dloI - 3.0f) * rstep + 1e-3f);
    int phi2 = (int)floorf((dhiI - 3.0f) * rstep - 1e-3f);
    plo2 = max(plo2, plo);
    phi2 = min(phi2, phi);
    if (plo2 > phi2) { plo2 = phi + 1; phi2 = phi; }   // no interior

    const int chunk = (len + SEGS - 1) >> 3;
    const int beg = plo + seg * chunk;
    const int end = min(beg + chunk, plo + len);

    float Prun = 1.0f;  // product of (1+1e-10 - dens) within my chunk
    float S = 0.0f;     // sum dens * local_absorption * feat within my chunk

    // --- boundary prefix (general path) ---
    const int aEnd = min(end, plo2);
    for (int p = beg; p < aEnd; ++p)
        general_step(vol, (float)p, A0, B0, A1, B1, A2, B2, S, Prun);

    // --- interior: s==1, dens==1/192 constant, unclamped loads ---
    const int i0b = max(beg, plo2);
    const int i1b = min(end, phi2 + 1);
    float qp = 1.0f, S2 = 0.0f;
    #pragma unroll 4
    for (int p = i0b; p < i1b; ++p) {
        const float pf = (float)p;
        const float fx = fmaf(A0, pf, B0);
        const float fy = fmaf(A1, pf, B1);
        const float fz = fmaf(A2, pf, B2);
        const float x0f = floorf(fx), y0f = floorf(fy), z0f = floorf(fz);
        const float wx = fx - x0f, wy = fy - y0f, wz = fz - z0f;
        const int ix = (int)x0f, iy = (int)y0f, iz = (int)z0f;
        const float* q0 = vol + ((iz * 128 + iy) * 128 + ix);
        const float v000 = q0[0],     v001 = q0[1];
        const float v010 = q0[128],   v011 = q0[129];
        const float v100 = q0[16384], v101 = q0[16385];
        const float v110 = q0[16512], v111 = q0[16513];
        const float x00 = fmaf(wx, v001 - v000, v000);
        const float x01 = fmaf(wx, v011 - v010, v010);
        const float x10 = fmaf(wx, v101 - v100, v100);
        const float x11 = fmaf(wx, v111 - v110, v110);
        const float y0v = fmaf(wy, x01 - x00, x00);
        const float y1v = fmaf(wy, x11 - x10, x10);
        const float feat = fmaf(wz, y1v - y0v, y0v);
        S2 = fmaf(qp, feat, S2);
        qp *= QF;
    }
    if (i1b > i0b) {
        const int kint = i1b - i0b;
        S = fmaf(Prun * (1.0f / 192.0f), S2, S);
        Prun *= exp2f((float)kint * L2Q);
    }

    // --- boundary suffix (general path) ---
    const int bBeg = max(beg, phi2 + 1);
    for (int p = bBeg; p < end; ++p)
        general_step(vol, (float)p, A0, B0, A1, B1, A2, B2, S, Prun);

    // ---- per-(seg,pixel) partials to LDS; wave 0 combines sequentially ----
    __shared__ float sP[SEGS][TILE_PIX];
    __shared__ float sS[SEGS][TILE_PIX];
    sP[seg][l] = Prun;
    sS[seg][l] = S;
    __syncthreads();

    if (tid < TILE_PIX) {
        float absorb = 1.0f, wS = 0.0f;
        #pragma unroll
        for (int s = 0; s < SEGS; ++s) {
            wS = fmaf(absorb, sS[s][l], wS);
            absorb *= sP[s][l];
        }
        // opacity from absorb: prod(1-dens) vs prod(1+1e-10-dens) differ <2e-8
        const float g = (3.0f * wS + (1.0f - absorb)) * 0.25f;
        out[h * 256 + w] = g;

        // wave-0 stats reduction over the 64 tile pixels
        float vs = g, vq = g * g, vmn = g, vmx = g;
        #pragma unroll
        for (int off = 1; off < 64; off <<= 1) {
            vs += __shfl_xor(vs, off);
            vq += __shfl_xor(vq, off);
            vmn = fminf(vmn, __shfl_xor(vmn, off));
            vmx = fmaxf(vmx, __shfl_xor(vmx, off));
        }
        if (l == 0) {
            part[blockIdx.x]             = vs;
            part[N_BLK + blockIdx.x]     = vq;
            part[2 * N_BLK + blockIdx.x] = vmn;
            part[3 * N_BLK + blockIdx.x] = vmx;
        }
    }
}

// Every block redundantly reduces the 1024 partials (L2/L3-hot),
// then normalizes its own 256 pixels. No cross-block ordering needed.
__global__ __launch_bounds__(256) void finish_kernel(
    float* __restrict__ out,
    const float* __restrict__ part)
{
    const int tid = threadIdx.x;
    __shared__ float s_s[4], s_q[4], s_n[4], s_x[4];
    __shared__ float s_fin[4];

    float fs  = part[tid]               + part[tid + 256]
              + part[tid + 512]         + part[tid + 768];
    float fq  = part[N_BLK + tid]       + part[N_BLK + tid + 256]
              + part[N_BLK + tid + 512] + part[N_BLK + tid + 768];
    float fn  = fminf(fminf(part[2 * N_BLK + tid],       part[2 * N_BLK + tid + 256]),
                      fminf(part[2 * N_BLK + tid + 512], part[2 * N_BLK + tid + 768]));
    float fx2 = fmaxf(fmaxf(part[3 * N_BLK + tid],       part[3 * N_BLK + tid + 256]),
                      fmaxf(part[3 * N_BLK + tid + 512], part[3 * N_BLK + tid + 768]));
    #pragma unroll
    for (int off = 1; off < 64; off <<= 1) {
        fs += __shfl_xor(fs, off);
        fq += __shfl_xor(fq, off);
        fn  = fminf(fn,  __shfl_xor(fn, off));
        fx2 = fmaxf(fx2, __shfl_xor(fx2, off));
    }
    const int wave = tid >> 6;
    const int lane = tid & 63;
    if (lane == 0) { s_s[wave] = fs; s_q[wave] = fq; s_n[wave] = fn; s_x[wave] = fx2; }
    __syncthreads();
    if (tid == 0) {
        const float tsum = s_s[0] + s_s[1] + s_s[2] + s_s[3];
        const float tsq  = s_q[0] + s_q[1] + s_q[2] + s_q[3];
        const float tmn  = fminf(fminf(s_n[0], s_n[1]), fminf(s_n[2], s_n[3]));
        const float tmx  = fmaxf(fmaxf(s_x[0], s_x[1]), fmaxf(s_x[2], s_x[3]));
        const float N = (float)N_PIX;
        const float mean = tsum / N;
        float var = (tsq - N * mean * mean) / (N - 1.0f);
        if (var < 0.0f) var = 0.0f;
        const float denom = sqrtf(var) + 1e-8f;
        s_fin[0] = mean;
        s_fin[1] = denom;
        s_fin[2] = (tmn - mean) / denom;   // std.min
        s_fin[3] = (tmx - mean) / denom;   // std.max
    }
    __syncthreads();

    const float mean = s_fin[0];
    const float rdenom = 1.0f / s_fin[1];
    const float smin = s_fin[2];
    const float rrange = 1.0f / (s_fin[3] - smin + 1e-8f);
    const int i = blockIdx.x * 256 + tid;
    const float sv = (out[i] - mean) * rdenom;
    out[i] = (sv - smin + 1e-8f) * rrange;
}

extern "C" void kernel_launch(void* const* d_in, const int* in_sizes, int n_in,
                              void* d_out, int out_size, void* d_ws, size_t ws_size,
                              hipStream_t stream)
{
    const float* vol = (const float*)d_in[0];
    const float* Rm  = (const float*)d_in[1];
    const float* Tv  = (const float*)d_in[2];
    float* out = (float*)d_out;
    float* part = (float*)d_ws;   // 4 * N_BLK floats = 16 KB

    hipLaunchKernelGGL(render_kernel, dim3(N_BLK), dim3(THREADS), 0, stream,
                       vol, Rm, Tv, out, part);
    hipLaunchKernelGGL(finish_kernel, dim3(N_PIX / 256), dim3(256), 0, stream,
                       out, part);
}